// Round 1
// baseline (2468.615 us; speedup 1.0000x reference)
//
#include <hip/hip_runtime.h>

// Decoder layer: x + attn(LN1(x)); then + FFN(LN2(.))
// B=2, S=2048, D=1024, H=16, DK=64, FF=4096. All fp32 in/out; f16 MFMA inside.

#define S_LEN 2048
#define DMODEL 1024
#define NHEADS 16
#define FFDIM 4096
#define MROWS 4096   // B*S

typedef _Float16 f16;
typedef _Float16 f16x8 __attribute__((ext_vector_type(8)));
typedef float f32x4 __attribute__((ext_vector_type(4)));
typedef unsigned long long u64;
typedef unsigned long long u64x2 __attribute__((ext_vector_type(2)));

union Frag { f16x8 h; u64 q[2]; };

__device__ __forceinline__ f32x4 mfma16(f16x8 a, f16x8 b, f32x4 c) {
  return __builtin_amdgcn_mfma_f32_16x16x32_f16(a, b, c, 0, 0, 0);
}

// ---------------- weight transpose+convert: W[K][N] fp32 -> Wt[N][K] f16 ----
__global__ __launch_bounds__(256) void wtrans_kernel(const float* __restrict__ W,
                                                     f16* __restrict__ Wt,
                                                     int K, int N) {
  __shared__ f16 tile[32][33];
  const int n0 = blockIdx.x * 32, k0 = blockIdx.y * 32;
  const int tx = threadIdx.x & 31, ty = threadIdx.x >> 5;  // 32 x 8
  for (int i = 0; i < 4; i++) {
    int k = ty + i * 8;
    tile[k][tx] = (f16)W[(size_t)(k0 + k) * N + n0 + tx];
  }
  __syncthreads();
  for (int i = 0; i < 4; i++) {
    int n = ty + i * 8;
    Wt[(size_t)(n0 + n) * K + k0 + tx] = tile[tx][n];
  }
}

__global__ void bias_concat_kernel(const float* __restrict__ bq,
                                   const float* __restrict__ bk,
                                   const float* __restrict__ bv,
                                   float* __restrict__ out) {
  int i = blockIdx.x * 256 + threadIdx.x;  // 3072 total
  float v = (i < 1024) ? bq[i] : (i < 2048) ? bk[i - 1024] : bv[i - 2048];
  out[i] = v;
}

// ---------------- LayerNorm fp32 -> f16 ------------------------------------
__global__ __launch_bounds__(256) void ln_kernel(const float* __restrict__ x,
                                                 const float* __restrict__ gw,
                                                 const float* __restrict__ bw,
                                                 f16* __restrict__ out) {
  const int row = blockIdx.x, t = threadIdx.x;
  const float* xr = x + (size_t)row * DMODEL;
  float4 v = *(const float4*)(xr + t * 4);
  float s = v.x + v.y + v.z + v.w;
  float s2 = v.x * v.x + v.y * v.y + v.z * v.z + v.w * v.w;
  for (int off = 1; off < 64; off <<= 1) {
    s += __shfl_xor(s, off);
    s2 += __shfl_xor(s2, off);
  }
  __shared__ float red[8];
  const int w = t >> 6, lane = t & 63;
  if (lane == 0) { red[w] = s; red[w + 4] = s2; }
  __syncthreads();
  s = red[0] + red[1] + red[2] + red[3];
  s2 = red[4] + red[5] + red[6] + red[7];
  float mu = s * (1.0f / DMODEL);
  float var = s2 * (1.0f / DMODEL) - mu * mu;
  float rstd = rsqrtf(var + 1e-6f);
  float4 g4 = *(const float4*)(gw + t * 4);
  float4 b4 = *(const float4*)(bw + t * 4);
  union { f16 h[4]; u64 q; } o;
  o.h[0] = (f16)((v.x - mu) * rstd * g4.x + b4.x);
  o.h[1] = (f16)((v.y - mu) * rstd * g4.y + b4.y);
  o.h[2] = (f16)((v.z - mu) * rstd * g4.z + b4.z);
  o.h[3] = (f16)((v.w - mu) * rstd * g4.w + b4.w);
  *(u64*)(out + (size_t)row * DMODEL + t * 4) = o.q;
}

// ---------------- GEMM: C[M][N] = A[M][K](f16) @ Bt[N][K](f16)^T + bias -----
// epilogue: optional relu, optional fp32 residual add, fp32 and/or f16 output.
__global__ __launch_bounds__(256) void gemm_f16(const f16* __restrict__ A, int lda,
                                                const f16* __restrict__ Bt,
                                                const float* __restrict__ bias,
                                                const float* __restrict__ res,
                                                float* __restrict__ outf,
                                                f16* __restrict__ outh, int ldo,
                                                int N, int K, int relu) {
  __shared__ f16 As[128][40];  // pad: stride 80B -> <=2-way bank conflict (free)
  __shared__ f16 Bs[128][40];
  const int m0 = blockIdx.y * 128, n0 = blockIdx.x * 128;
  const int t = threadIdx.x;
  const int lane = t & 63, w = t >> 6;
  const int wr = w >> 1, wc = w & 1;       // 2x2 waves of 64x64
  const int rA = lane & 15, g = lane >> 4;
  const int srow = t >> 2, skoff = (t & 3) * 8;
  f32x4 acc[4][4] = {};
  for (int k0 = 0; k0 < K; k0 += 32) {
    __syncthreads();
    for (int p = 0; p < 2; p++) {
      int r = srow + p * 64;
      u64x2 va = *(const u64x2*)(A + (size_t)(m0 + r) * lda + k0 + skoff);
      *(u64x2*)(&As[r][skoff]) = va;
      u64x2 vb = *(const u64x2*)(Bt + (size_t)(n0 + r) * K + k0 + skoff);
      *(u64x2*)(&Bs[r][skoff]) = vb;
    }
    __syncthreads();
    Frag a[4], b[4];
    for (int mt = 0; mt < 4; mt++) {
      const f16* p = &As[wr * 64 + mt * 16 + rA][4 * g];
      a[mt].q[0] = *(const u64*)p;
      a[mt].q[1] = *(const u64*)(p + 16);
    }
    for (int nt = 0; nt < 4; nt++) {
      const f16* p = &Bs[wc * 64 + nt * 16 + rA][4 * g];
      b[nt].q[0] = *(const u64*)p;
      b[nt].q[1] = *(const u64*)(p + 16);
    }
    for (int mt = 0; mt < 4; mt++)
      for (int nt = 0; nt < 4; nt++)
        acc[mt][nt] = mfma16(a[mt].h, b[nt].h, acc[mt][nt]);
  }
  for (int mt = 0; mt < 4; mt++) {
    for (int nt = 0; nt < 4; nt++) {
      const int col = n0 + wc * 64 + nt * 16 + rA;
      const int rowb = m0 + wr * 64 + mt * 16 + g * 4;
      const float bs = bias[col];
      for (int r = 0; r < 4; r++) {
        float v = acc[mt][nt][r] + bs;
        if (relu) v = fmaxf(v, 0.0f);
        if (res) v += res[(size_t)(rowb + r) * N + col];
        if (outf) outf[(size_t)(rowb + r) * N + col] = v;
        if (outh) outh[(size_t)(rowb + r) * ldo + col] = (f16)v;
      }
    }
  }
}

// ---------------- V transpose: qkv v-cols -> vt[bh*64+dk][s] ----------------
__global__ __launch_bounds__(256) void vtrans_kernel(const f16* __restrict__ qkv,
                                                     f16* __restrict__ vt) {
  const int bh = blockIdx.y;                 // 0..31
  const int s0 = blockIdx.x * 64;
  const int b = bh >> 4, h = bh & 15;
  __shared__ f16 tile[64][72];               // [s][dk]
  const int t = threadIdx.x;
  for (int pass = 0; pass < 2; pass++) {
    int sl = (t >> 3) + pass * 32;
    int dk0 = (t & 7) * 8;
    u64x2 v = *(const u64x2*)(qkv + (size_t)(b * S_LEN + s0 + sl) * 3072 + 2048 + h * 64 + dk0);
    *(u64x2*)(&tile[sl][dk0]) = v;
  }
  __syncthreads();
  for (int pass = 0; pass < 2; pass++) {
    int dk = (t >> 3) + pass * 32;
    int sc = (t & 7) * 8;
    union { u64x2 q; f16 u[8]; } o;
    for (int j = 0; j < 8; j++) o.u[j] = tile[sc + j][dk];
    *(u64x2*)(vt + (size_t)(bh * 64 + dk) * S_LEN + s0 + sc) = o.q;
  }
}

// ---------------- flash attention: 1 wave per 16 q rows ---------------------
__global__ __launch_bounds__(64) void attn_kernel(const f16* __restrict__ qkv,
                                                  const f16* __restrict__ vt,
                                                  f16* __restrict__ attn_out) {
  const int bid = blockIdx.x;
  const int qt = bid & 127;   // S/16
  const int bh = bid >> 7;    // 0..31
  const int b = bh >> 4, h = bh & 15;
  const int lane = threadIdx.x;
  const int rA = lane & 15, g = lane >> 4;

  const f16* Qp = qkv + (size_t)(b * S_LEN + qt * 16 + rA) * 3072 + h * 64;
  const f16* Kbase = qkv + (size_t)(b * S_LEN) * 3072 + 1024 + h * 64;
  const f16* Vbase = vt + (size_t)(bh * 64) * S_LEN;

  __shared__ f16 P[16][68];  // stride 68 elems -> conflict-free frag reads

  Frag aq[2];
  for (int kt = 0; kt < 2; kt++) {
    aq[kt].q[0] = *(const u64*)(Qp + kt * 32 + 4 * g);
    aq[kt].q[1] = *(const u64*)(Qp + kt * 32 + 16 + 4 * g);
  }

  float mR[4], lR[4];
  f32x4 o[4] = {};
  for (int r = 0; r < 4; r++) { mR[r] = -3.0e38f; lR[r] = 0.0f; }

  for (int kv0 = 0; kv0 < S_LEN; kv0 += 64) {
    f32x4 s[4] = {};
    for (int nt = 0; nt < 4; nt++) {
      const f16* Kp = Kbase + (size_t)(kv0 + nt * 16 + rA) * 3072;
      for (int kt = 0; kt < 2; kt++) {
        Frag bk;
        bk.q[0] = *(const u64*)(Kp + kt * 32 + 4 * g);
        bk.q[1] = *(const u64*)(Kp + kt * 32 + 16 + 4 * g);
        s[nt] = mfma16(aq[kt].h, bk.h, s[nt]);
      }
    }
    for (int nt = 0; nt < 4; nt++) s[nt] = s[nt] * 0.125f;  // 1/sqrt(64)
    float alpha[4];
    for (int r = 0; r < 4; r++) {
      float mx = fmaxf(fmaxf(s[0][r], s[1][r]), fmaxf(s[2][r], s[3][r]));
      mx = fmaxf(mx, __shfl_xor(mx, 1));
      mx = fmaxf(mx, __shfl_xor(mx, 2));
      mx = fmaxf(mx, __shfl_xor(mx, 4));
      mx = fmaxf(mx, __shfl_xor(mx, 8));
      float mn = fmaxf(mR[r], mx);
      alpha[r] = exp2f((mR[r] - mn) * 1.44269504f);
      mR[r] = mn;
    }
    for (int nt = 0; nt < 4; nt++)
      for (int r = 0; r < 4; r++)
        s[nt][r] = exp2f((s[nt][r] - mR[r]) * 1.44269504f);
    for (int r = 0; r < 4; r++) {
      float rsum = s[0][r] + s[1][r] + s[2][r] + s[3][r];
      rsum += __shfl_xor(rsum, 1);
      rsum += __shfl_xor(rsum, 2);
      rsum += __shfl_xor(rsum, 4);
      rsum += __shfl_xor(rsum, 8);
      lR[r] = lR[r] * alpha[r] + rsum;
      for (int nt = 0; nt < 4; nt++) o[nt][r] *= alpha[r];
    }
    for (int nt = 0; nt < 4; nt++)
      for (int r = 0; r < 4; r++)
        P[g * 4 + r][nt * 16 + rA] = (f16)s[nt][r];
    __syncthreads();
    for (int kt2 = 0; kt2 < 2; kt2++) {
      Frag pa;
      pa.q[0] = *(const u64*)(&P[rA][kt2 * 32 + 4 * g]);
      pa.q[1] = *(const u64*)(&P[rA][kt2 * 32 + 16 + 4 * g]);
      for (int nt = 0; nt < 4; nt++) {
        const f16* Vp = Vbase + (size_t)(nt * 16 + rA) * S_LEN + kv0 + kt2 * 32;
        Frag bv;
        bv.q[0] = *(const u64*)(Vp + 4 * g);
        bv.q[1] = *(const u64*)(Vp + 16 + 4 * g);
        o[nt] = mfma16(pa.h, bv.h, o[nt]);
      }
    }
    __syncthreads();
  }
  const int orow = b * S_LEN + qt * 16 + g * 4;
  for (int nt = 0; nt < 4; nt++)
    for (int r = 0; r < 4; r++)
      attn_out[(size_t)(orow + r) * DMODEL + h * 64 + nt * 16 + rA] =
          (f16)(o[nt][r] / lR[r]);
}

// ---------------------------------------------------------------------------
extern "C" void kernel_launch(void* const* d_in, const int* in_sizes, int n_in,
                              void* d_out, int out_size, void* d_ws, size_t ws_size,
                              hipStream_t stream) {
  const float* x     = (const float*)d_in[0];
  const float* Wq    = (const float*)d_in[1];
  const float* bq    = (const float*)d_in[2];
  const float* Wk    = (const float*)d_in[3];
  const float* bk    = (const float*)d_in[4];
  const float* Wv    = (const float*)d_in[5];
  const float* bv    = (const float*)d_in[6];
  const float* Wo    = (const float*)d_in[7];
  const float* bo    = (const float*)d_in[8];
  const float* W1    = (const float*)d_in[9];
  const float* b1    = (const float*)d_in[10];
  const float* W2    = (const float*)d_in[11];
  const float* b2    = (const float*)d_in[12];
  const float* ln1g  = (const float*)d_in[13];
  const float* ln1b  = (const float*)d_in[14];
  const float* ln2g  = (const float*)d_in[15];
  const float* ln2b  = (const float*)d_in[16];
  float* out = (float*)d_out;
  char* ws = (char*)d_ws;

  size_t off = 0;
  f16* wqkv_t = (f16*)(ws + off); off += (size_t)3072 * 1024 * 2;   // 6 MB
  f16* wo_t   = (f16*)(ws + off); off += (size_t)1024 * 1024 * 2;   // 2 MB
  f16* w1_t   = (f16*)(ws + off); off += (size_t)4096 * 1024 * 2;   // 8 MB
  f16* w2_t   = (f16*)(ws + off); off += (size_t)1024 * 4096 * 2;   // 8 MB
  float* bqkv = (float*)(ws + off); off += 3072 * 4;                // 12 KB
  f16* regB   = (f16*)(ws + off); off += (size_t)MROWS * 1024 * 2;  // 8 MB (xln/attn_out/xln2)
  f16* qkv    = (f16*)(ws + off); off += (size_t)MROWS * 3072 * 2;  // 24 MB
  f16* vt     = (f16*)(ws + off); off += (size_t)MROWS * 1024 * 2;  // 8 MB
  f16* hbuf   = qkv;  // overlay: qkv+vt (32MB) dead after attention; FFN h = 32MB

  // 1. weights -> f16 transposed
  wtrans_kernel<<<dim3(32, 32), 256, 0, stream>>>(Wq, wqkv_t, 1024, 1024);
  wtrans_kernel<<<dim3(32, 32), 256, 0, stream>>>(Wk, wqkv_t + (size_t)1024 * 1024, 1024, 1024);
  wtrans_kernel<<<dim3(32, 32), 256, 0, stream>>>(Wv, wqkv_t + (size_t)2048 * 1024, 1024, 1024);
  wtrans_kernel<<<dim3(32, 32), 256, 0, stream>>>(Wo, wo_t, 1024, 1024);
  wtrans_kernel<<<dim3(128, 32), 256, 0, stream>>>(W1, w1_t, 1024, 4096);
  wtrans_kernel<<<dim3(32, 128), 256, 0, stream>>>(W2, w2_t, 4096, 1024);
  bias_concat_kernel<<<12, 256, 0, stream>>>(bq, bk, bv, bqkv);

  // 2. LN1(x) -> regB (f16)
  ln_kernel<<<MROWS, 256, 0, stream>>>(x, ln1g, ln1b, regB);

  // 3. fused QKV projection: [4096,1024] @ [1024,3072]
  gemm_f16<<<dim3(24, 32), 256, 0, stream>>>(regB, 1024, wqkv_t, bqkv,
                                             nullptr, nullptr, qkv, 3072,
                                             3072, 1024, 0);
  // 4. V -> [bh*64+dk][s]
  vtrans_kernel<<<dim3(32, 32), 256, 0, stream>>>(qkv, vt);

  // 5. attention -> regB (f16), one wave per 16 q-rows
  attn_kernel<<<4096, 64, 0, stream>>>(qkv, vt, regB);

  // 6. O projection + residual x -> d_out (fp32)
  gemm_f16<<<dim3(8, 32), 256, 0, stream>>>(regB, 1024, wo_t, bo,
                                            x, out, nullptr, 0,
                                            1024, 1024, 0);
  // 7. LN2(d_out) -> regB
  ln_kernel<<<MROWS, 256, 0, stream>>>(out, ln2g, ln2b, regB);

  // 8. FFN1 + ReLU: [4096,1024]@[1024,4096] -> hbuf (f16)
  gemm_f16<<<dim3(32, 32), 256, 0, stream>>>(regB, 1024, w1_t, b1,
                                             nullptr, nullptr, hbuf, 4096,
                                             4096, 1024, 1);
  // 9. FFN2 + residual: [4096,4096]@[4096,1024] + d_out -> d_out
  gemm_f16<<<dim3(8, 32), 256, 0, stream>>>(hbuf, 4096, w2_t, b2,
                                            out, out, nullptr, 0,
                                            1024, 4096, 0);
}

// Round 2
// 1367.624 us; speedup vs baseline: 1.8050x; 1.8050x over previous
//
#include <hip/hip_runtime.h>

// Decoder layer: x + attn(LN1(x)); then + FFN(LN2(.))
// B=2, S=2048, D=1024, H=16, DK=64, FF=4096. fp32 in/out; f16 MFMA inside.

#define S_LEN 2048
#define DMODEL 1024
#define NHEADS 16
#define FFDIM 4096
#define MROWS 4096   // B*S

typedef _Float16 f16;
typedef _Float16 f16x8 __attribute__((ext_vector_type(8)));
typedef float f32x4 __attribute__((ext_vector_type(4)));
typedef unsigned long long u64;
typedef unsigned long long u64x2 __attribute__((ext_vector_type(2)));

union Frag { f16x8 h; u64 q[2]; };

__device__ __forceinline__ f32x4 mfma16(f16x8 a, f16x8 b, f32x4 c) {
  return __builtin_amdgcn_mfma_f32_16x16x32_f16(a, b, c, 0, 0, 0);
}

typedef __attribute__((address_space(1))) const void gvoid;
typedef __attribute__((address_space(3))) void lvoid;

__device__ __forceinline__ void gload16(const f16* gp, f16* lp) {
  __builtin_amdgcn_global_load_lds((gvoid*)gp, (lvoid*)lp, 16, 0, 0);
}

// ---------------- weight transpose+convert: W[K][N] fp32 -> Wt[N][K] f16 ----
__global__ __launch_bounds__(256) void wtrans_kernel(const float* __restrict__ W,
                                                     f16* __restrict__ Wt,
                                                     int K, int N) {
  __shared__ f16 tile[32][33];
  const int n0 = blockIdx.x * 32, k0 = blockIdx.y * 32;
  const int tx = threadIdx.x & 31, ty = threadIdx.x >> 5;  // 32 x 8
  for (int i = 0; i < 4; i++) {
    int k = ty + i * 8;
    tile[k][tx] = (f16)W[(size_t)(k0 + k) * N + n0 + tx];
  }
  __syncthreads();
  for (int i = 0; i < 4; i++) {
    int n = ty + i * 8;
    Wt[(size_t)(n0 + n) * K + k0 + tx] = tile[tx][n];
  }
}

__global__ void bias_concat_kernel(const float* __restrict__ bq,
                                   const float* __restrict__ bk,
                                   const float* __restrict__ bv,
                                   float* __restrict__ out) {
  int i = blockIdx.x * 256 + threadIdx.x;  // 3072 total
  float v = (i < 1024) ? bq[i] : (i < 2048) ? bk[i - 1024] : bv[i - 2048];
  out[i] = v;
}

// ---------------- LayerNorm fp32 -> f16 ------------------------------------
__global__ __launch_bounds__(256) void ln_kernel(const float* __restrict__ x,
                                                 const float* __restrict__ gw,
                                                 const float* __restrict__ bw,
                                                 f16* __restrict__ out) {
  const int row = blockIdx.x, t = threadIdx.x;
  const float* xr = x + (size_t)row * DMODEL;
  float4 v = *(const float4*)(xr + t * 4);
  float s = v.x + v.y + v.z + v.w;
  float s2 = v.x * v.x + v.y * v.y + v.z * v.z + v.w * v.w;
  for (int off = 1; off < 64; off <<= 1) {
    s += __shfl_xor(s, off);
    s2 += __shfl_xor(s2, off);
  }
  __shared__ float red[8];
  const int w = t >> 6, lane = t & 63;
  if (lane == 0) { red[w] = s; red[w + 4] = s2; }
  __syncthreads();
  s = red[0] + red[1] + red[2] + red[3];
  s2 = red[4] + red[5] + red[6] + red[7];
  float mu = s * (1.0f / DMODEL);
  float var = s2 * (1.0f / DMODEL) - mu * mu;
  float rstd = rsqrtf(var + 1e-6f);
  float4 g4 = *(const float4*)(gw + t * 4);
  float4 b4 = *(const float4*)(bw + t * 4);
  union { f16 h[4]; u64 q; } o;
  o.h[0] = (f16)((v.x - mu) * rstd * g4.x + b4.x);
  o.h[1] = (f16)((v.y - mu) * rstd * g4.y + b4.y);
  o.h[2] = (f16)((v.z - mu) * rstd * g4.z + b4.z);
  o.h[3] = (f16)((v.w - mu) * rstd * g4.w + b4.w);
  *(u64*)(out + (size_t)row * DMODEL + t * 4) = o.q;
}

// ---------------- GEMM (m97 structure): C = A[M][K] @ Bt[N][K]^T + bias -----
// BK=64, global_load_lds width-16 staging, linear LDS, 2-barrier K-loop.
// 4 waves (2x2), wave tile (BM/2)x(BN/2), 16x16x32 f16 MFMA.
template <int BM, int BN>
__global__ __launch_bounds__(256, 2) void gemm2(const f16* __restrict__ A, int lda,
                                                const f16* __restrict__ Bt, int ldb,
                                                const float* __restrict__ bias,
                                                const float* __restrict__ res,
                                                float* __restrict__ outf,
                                                f16* __restrict__ outh, int ldo,
                                                int N, int K, int relu) {
  constexpr int MT = BM / 32, NT = BN / 32;
  __shared__ f16 As[BM * 64];
  __shared__ f16 Bs[BN * 64];
  const int m0 = blockIdx.y * BM, n0 = blockIdx.x * BN;
  const int t = threadIdx.x;
  const int lane = t & 63, w = t >> 6;
  const int wr = w >> 1, wc = w & 1;
  const int rA = lane & 15, g = lane >> 4;

  f32x4 acc[MT][NT] = {};

  for (int k0 = 0; k0 < K; k0 += 64) {
    __syncthreads();  // previous tile fully consumed
#pragma unroll
    for (int p = 0; p < BM / 32; p++) {
      const int chunk = p * 256 + w * 64 + lane;     // 16B chunk id
      const int row = chunk >> 3, cb = chunk & 7;    // 8 chunks per 64-elem row
      gload16(A + (size_t)(m0 + row) * lda + k0 + cb * 8,
              As + (size_t)(p * 256 + w * 64) * 8);  // uniform base; HW adds lane*16B
    }
#pragma unroll
    for (int p = 0; p < BN / 32; p++) {
      const int chunk = p * 256 + w * 64 + lane;
      const int row = chunk >> 3, cb = chunk & 7;
      gload16(Bt + (size_t)(n0 + row) * ldb + k0 + cb * 8,
              Bs + (size_t)(p * 256 + w * 64) * 8);
    }
    __syncthreads();  // drains vmcnt(0): tile resident

#pragma unroll
    for (int ks = 0; ks < 2; ks++) {
      Frag a[MT], b[NT];
#pragma unroll
      for (int mt = 0; mt < MT; mt++) {
        const f16* p = As + (size_t)(wr * (BM / 2) + mt * 16 + rA) * 64 + ks * 32 + 4 * g;
        a[mt].q[0] = *(const u64*)p;
        a[mt].q[1] = *(const u64*)(p + 16);
      }
#pragma unroll
      for (int nt = 0; nt < NT; nt++) {
        const f16* p = Bs + (size_t)(wc * (BN / 2) + nt * 16 + rA) * 64 + ks * 32 + 4 * g;
        b[nt].q[0] = *(const u64*)p;
        b[nt].q[1] = *(const u64*)(p + 16);
      }
#pragma unroll
      for (int mt = 0; mt < MT; mt++)
#pragma unroll
        for (int nt = 0; nt < NT; nt++)
          acc[mt][nt] = mfma16(a[mt].h, b[nt].h, acc[mt][nt]);
    }
  }

#pragma unroll
  for (int mt = 0; mt < MT; mt++) {
#pragma unroll
    for (int nt = 0; nt < NT; nt++) {
      const int col = n0 + wc * (BN / 2) + nt * 16 + rA;
      const int rowb = m0 + wr * (BM / 2) + mt * 16 + g * 4;
      const float bs = bias[col];
#pragma unroll
      for (int r = 0; r < 4; r++) {
        float v = acc[mt][nt][r] + bs;
        if (relu) v = fmaxf(v, 0.0f);
        if (res) v += res[(size_t)(rowb + r) * N + col];
        if (outf) outf[(size_t)(rowb + r) * N + col] = v;
        if (outh) outh[(size_t)(rowb + r) * ldo + col] = (f16)v;
      }
    }
  }
}

// ---------------- V transpose: qkv v-cols -> vt[bh*64+dk][s] ----------------
__global__ __launch_bounds__(256) void vtrans_kernel(const f16* __restrict__ qkv,
                                                     f16* __restrict__ vt) {
  const int bh = blockIdx.y;                 // 0..31
  const int s0 = blockIdx.x * 64;
  const int b = bh >> 4, h = bh & 15;
  __shared__ f16 tile[64][72];               // [s][dk]
  const int t = threadIdx.x;
  for (int pass = 0; pass < 2; pass++) {
    int sl = (t >> 3) + pass * 32;
    int dk0 = (t & 7) * 8;
    u64x2 v = *(const u64x2*)(qkv + (size_t)(b * S_LEN + s0 + sl) * 3072 + 2048 + h * 64 + dk0);
    *(u64x2*)(&tile[sl][dk0]) = v;
  }
  __syncthreads();
  for (int pass = 0; pass < 2; pass++) {
    int dk = (t >> 3) + pass * 32;
    int sc = (t & 7) * 8;
    union { u64x2 q; f16 u[8]; } o;
    for (int j = 0; j < 8; j++) o.u[j] = tile[sc + j][dk];
    *(u64x2*)(vt + (size_t)(bh * 64 + dk) * S_LEN + s0 + sc) = o.q;
  }
}

// ---------------- flash attention: 1 wave per 16 q rows ---------------------
__global__ __launch_bounds__(64) void attn_kernel(const f16* __restrict__ qkv,
                                                  const f16* __restrict__ vt,
                                                  f16* __restrict__ attn_out) {
  const int bid = blockIdx.x;
  const int qt = bid & 127;   // S/16
  const int bh = bid >> 7;    // 0..31
  const int b = bh >> 4, h = bh & 15;
  const int lane = threadIdx.x;
  const int rA = lane & 15, g = lane >> 4;

  const f16* Qp = qkv + (size_t)(b * S_LEN + qt * 16 + rA) * 3072 + h * 64;
  const f16* Kbase = qkv + (size_t)(b * S_LEN) * 3072 + 1024 + h * 64;
  const f16* Vbase = vt + (size_t)(bh * 64) * S_LEN;

  __shared__ f16 P[16][68];  // stride 68 elems -> conflict-free frag reads

  Frag aq[2];
  for (int kt = 0; kt < 2; kt++) {
    aq[kt].q[0] = *(const u64*)(Qp + kt * 32 + 4 * g);
    aq[kt].q[1] = *(const u64*)(Qp + kt * 32 + 16 + 4 * g);
  }

  float mR[4], lR[4];
  f32x4 o[4] = {};
  for (int r = 0; r < 4; r++) { mR[r] = -3.0e38f; lR[r] = 0.0f; }

  for (int kv0 = 0; kv0 < S_LEN; kv0 += 64) {
    f32x4 s[4] = {};
    for (int nt = 0; nt < 4; nt++) {
      const f16* Kp = Kbase + (size_t)(kv0 + nt * 16 + rA) * 3072;
      for (int kt = 0; kt < 2; kt++) {
        Frag bk;
        bk.q[0] = *(const u64*)(Kp + kt * 32 + 4 * g);
        bk.q[1] = *(const u64*)(Kp + kt * 32 + 16 + 4 * g);
        s[nt] = mfma16(aq[kt].h, bk.h, s[nt]);
      }
    }
    for (int nt = 0; nt < 4; nt++) s[nt] = s[nt] * 0.125f;  // 1/sqrt(64)
    float alpha[4];
    for (int r = 0; r < 4; r++) {
      float mx = fmaxf(fmaxf(s[0][r], s[1][r]), fmaxf(s[2][r], s[3][r]));
      mx = fmaxf(mx, __shfl_xor(mx, 1));
      mx = fmaxf(mx, __shfl_xor(mx, 2));
      mx = fmaxf(mx, __shfl_xor(mx, 4));
      mx = fmaxf(mx, __shfl_xor(mx, 8));
      float mn = fmaxf(mR[r], mx);
      alpha[r] = exp2f((mR[r] - mn) * 1.44269504f);
      mR[r] = mn;
    }
    for (int nt = 0; nt < 4; nt++)
      for (int r = 0; r < 4; r++)
        s[nt][r] = exp2f((s[nt][r] - mR[r]) * 1.44269504f);
    for (int r = 0; r < 4; r++) {
      float rsum = s[0][r] + s[1][r] + s[2][r] + s[3][r];
      rsum += __shfl_xor(rsum, 1);
      rsum += __shfl_xor(rsum, 2);
      rsum += __shfl_xor(rsum, 4);
      rsum += __shfl_xor(rsum, 8);
      lR[r] = lR[r] * alpha[r] + rsum;
      for (int nt = 0; nt < 4; nt++) o[nt][r] *= alpha[r];
    }
    for (int nt = 0; nt < 4; nt++)
      for (int r = 0; r < 4; r++)
        P[g * 4 + r][nt * 16 + rA] = (f16)s[nt][r];
    __syncthreads();
    for (int kt2 = 0; kt2 < 2; kt2++) {
      Frag pa;
      pa.q[0] = *(const u64*)(&P[rA][kt2 * 32 + 4 * g]);
      pa.q[1] = *(const u64*)(&P[rA][kt2 * 32 + 16 + 4 * g]);
      for (int nt = 0; nt < 4; nt++) {
        const f16* Vp = Vbase + (size_t)(nt * 16 + rA) * S_LEN + kv0 + kt2 * 32;
        Frag bv;
        bv.q[0] = *(const u64*)(Vp + 4 * g);
        bv.q[1] = *(const u64*)(Vp + 16 + 4 * g);
        o[nt] = mfma16(pa.h, bv.h, o[nt]);
      }
    }
    __syncthreads();
  }
  const int orow = b * S_LEN + qt * 16 + g * 4;
  for (int nt = 0; nt < 4; nt++)
    for (int r = 0; r < 4; r++)
      attn_out[(size_t)(orow + r) * DMODEL + h * 64 + nt * 16 + rA] =
          (f16)(o[nt][r] / lR[r]);
}

// ---------------------------------------------------------------------------
extern "C" void kernel_launch(void* const* d_in, const int* in_sizes, int n_in,
                              void* d_out, int out_size, void* d_ws, size_t ws_size,
                              hipStream_t stream) {
  const float* x     = (const float*)d_in[0];
  const float* Wq    = (const float*)d_in[1];
  const float* bq    = (const float*)d_in[2];
  const float* Wk    = (const float*)d_in[3];
  const float* bk    = (const float*)d_in[4];
  const float* Wv    = (const float*)d_in[5];
  const float* bv    = (const float*)d_in[6];
  const float* Wo    = (const float*)d_in[7];
  const float* bo    = (const float*)d_in[8];
  const float* W1    = (const float*)d_in[9];
  const float* b1    = (const float*)d_in[10];
  const float* W2    = (const float*)d_in[11];
  const float* b2    = (const float*)d_in[12];
  const float* ln1g  = (const float*)d_in[13];
  const float* ln1b  = (const float*)d_in[14];
  const float* ln2g  = (const float*)d_in[15];
  const float* ln2b  = (const float*)d_in[16];
  float* out = (float*)d_out;
  char* ws = (char*)d_ws;

  size_t off = 0;
  f16* wqkv_t = (f16*)(ws + off); off += (size_t)3072 * 1024 * 2;   // 6 MB
  f16* wo_t   = (f16*)(ws + off); off += (size_t)1024 * 1024 * 2;   // 2 MB
  f16* w1_t   = (f16*)(ws + off); off += (size_t)4096 * 1024 * 2;   // 8 MB
  f16* w2_t   = (f16*)(ws + off); off += (size_t)1024 * 4096 * 2;   // 8 MB
  float* bqkv = (float*)(ws + off); off += 3072 * 4;                // 12 KB
  f16* regB   = (f16*)(ws + off); off += (size_t)MROWS * 1024 * 2;  // 8 MB (xln/attn_out/xln2)
  f16* qkv    = (f16*)(ws + off); off += (size_t)MROWS * 3072 * 2;  // 24 MB
  f16* vt     = (f16*)(ws + off); off += (size_t)MROWS * 1024 * 2;  // 8 MB
  f16* hbuf   = qkv;  // overlay: qkv+vt (32MB) dead after attention; FFN h = 32MB

  // 1. weights -> f16 transposed
  wtrans_kernel<<<dim3(32, 32), 256, 0, stream>>>(Wq, wqkv_t, 1024, 1024);
  wtrans_kernel<<<dim3(32, 32), 256, 0, stream>>>(Wk, wqkv_t + (size_t)1024 * 1024, 1024, 1024);
  wtrans_kernel<<<dim3(32, 32), 256, 0, stream>>>(Wv, wqkv_t + (size_t)2048 * 1024, 1024, 1024);
  wtrans_kernel<<<dim3(32, 32), 256, 0, stream>>>(Wo, wo_t, 1024, 1024);
  wtrans_kernel<<<dim3(128, 32), 256, 0, stream>>>(W1, w1_t, 1024, 4096);
  wtrans_kernel<<<dim3(32, 128), 256, 0, stream>>>(W2, w2_t, 4096, 1024);
  bias_concat_kernel<<<12, 256, 0, stream>>>(bq, bk, bv, bqkv);

  // 2. LN1(x) -> regB (f16)
  ln_kernel<<<MROWS, 256, 0, stream>>>(x, ln1g, ln1b, regB);

  // 3. fused QKV projection: [4096,1024] @ [1024,3072]
  gemm2<128, 128><<<dim3(24, 32), 256, 0, stream>>>(regB, 1024, wqkv_t, 1024, bqkv,
                                                    nullptr, nullptr, qkv, 3072,
                                                    3072, 1024, 0);
  // 4. V -> [bh*64+dk][s]
  vtrans_kernel<<<dim3(32, 32), 256, 0, stream>>>(qkv, vt);

  // 5. attention -> regB (f16), one wave per 16 q-rows
  attn_kernel<<<4096, 64, 0, stream>>>(qkv, vt, regB);

  // 6. O projection + residual x -> d_out (fp32); 128x64 tiles -> 512 blocks
  gemm2<128, 64><<<dim3(16, 32), 256, 0, stream>>>(regB, 1024, wo_t, 1024, bo,
                                                   x, out, nullptr, 0,
                                                   1024, 1024, 0);
  // 7. LN2(d_out) -> regB
  ln_kernel<<<MROWS, 256, 0, stream>>>(out, ln2g, ln2b, regB);

  // 8. FFN1 + ReLU: [4096,1024]@[1024,4096] -> hbuf (f16)
  gemm2<128, 128><<<dim3(32, 32), 256, 0, stream>>>(regB, 1024, w1_t, 1024, b1,
                                                    nullptr, nullptr, hbuf, 4096,
                                                    4096, 1024, 1);
  // 9. FFN2 + residual: [4096,4096]@[4096,1024] + d_out -> d_out; 512 blocks
  gemm2<128, 64><<<dim3(16, 32), 256, 0, stream>>>(hbuf, 4096, w2_t, 4096, b2,
                                                   out, out, nullptr, 0,
                                                   1024, 4096, 0);
}

// Round 3
// 1040.484 us; speedup vs baseline: 2.3726x; 1.3144x over previous
//
#include <hip/hip_runtime.h>

// Decoder layer: x + attn(LN1(x)); then + FFN(LN2(.))
// B=2, S=2048, D=1024, H=16, DK=64, FF=4096. fp32 in/out; f16 MFMA inside.

#define S_LEN 2048
#define DMODEL 1024
#define NHEADS 16
#define FFDIM 4096
#define MROWS 4096   // B*S

typedef _Float16 f16;
typedef _Float16 f16x8 __attribute__((ext_vector_type(8)));
typedef float f32x4 __attribute__((ext_vector_type(4)));
typedef unsigned long long u64;
typedef unsigned long long u64x2 __attribute__((ext_vector_type(2)));

union Frag { f16x8 h; u64 q[2]; };

__device__ __forceinline__ f32x4 mfma16(f16x8 a, f16x8 b, f32x4 c) {
  return __builtin_amdgcn_mfma_f32_16x16x32_f16(a, b, c, 0, 0, 0);
}

typedef __attribute__((address_space(1))) const void gvoid;
typedef __attribute__((address_space(3))) void lvoid;

__device__ __forceinline__ void gload16(const f16* gp, f16* lp) {
  __builtin_amdgcn_global_load_lds((gvoid*)gp, (lvoid*)lp, 16, 0, 0);
}

// ---------------- weight transpose+convert: W[K][N] fp32 -> Wt[N][K] f16 ----
__global__ __launch_bounds__(256) void wtrans_kernel(const float* __restrict__ W,
                                                     f16* __restrict__ Wt,
                                                     int K, int N) {
  __shared__ f16 tile[32][33];
  const int n0 = blockIdx.x * 32, k0 = blockIdx.y * 32;
  const int tx = threadIdx.x & 31, ty = threadIdx.x >> 5;  // 32 x 8
  for (int i = 0; i < 4; i++) {
    int k = ty + i * 8;
    tile[k][tx] = (f16)W[(size_t)(k0 + k) * N + n0 + tx];
  }
  __syncthreads();
  for (int i = 0; i < 4; i++) {
    int n = ty + i * 8;
    Wt[(size_t)(n0 + n) * K + k0 + tx] = tile[tx][n];
  }
}

__global__ void bias_concat_kernel(const float* __restrict__ bq,
                                   const float* __restrict__ bk,
                                   const float* __restrict__ bv,
                                   float* __restrict__ out) {
  int i = blockIdx.x * 256 + threadIdx.x;  // 3072 total
  float v = (i < 1024) ? bq[i] : (i < 2048) ? bk[i - 1024] : bv[i - 2048];
  out[i] = v;
}

// ---------------- LayerNorm fp32 -> f16 ------------------------------------
__global__ __launch_bounds__(256) void ln_kernel(const float* __restrict__ x,
                                                 const float* __restrict__ gw,
                                                 const float* __restrict__ bw,
                                                 f16* __restrict__ out) {
  const int row = blockIdx.x, t = threadIdx.x;
  const float* xr = x + (size_t)row * DMODEL;
  float4 v = *(const float4*)(xr + t * 4);
  float s = v.x + v.y + v.z + v.w;
  float s2 = v.x * v.x + v.y * v.y + v.z * v.z + v.w * v.w;
  for (int off = 1; off < 64; off <<= 1) {
    s += __shfl_xor(s, off);
    s2 += __shfl_xor(s2, off);
  }
  __shared__ float red[8];
  const int w = t >> 6, lane = t & 63;
  if (lane == 0) { red[w] = s; red[w + 4] = s2; }
  __syncthreads();
  s = red[0] + red[1] + red[2] + red[3];
  s2 = red[4] + red[5] + red[6] + red[7];
  float mu = s * (1.0f / DMODEL);
  float var = s2 * (1.0f / DMODEL) - mu * mu;
  float rstd = rsqrtf(var + 1e-6f);
  float4 g4 = *(const float4*)(gw + t * 4);
  float4 b4 = *(const float4*)(bw + t * 4);
  union { f16 h[4]; u64 q; } o;
  o.h[0] = (f16)((v.x - mu) * rstd * g4.x + b4.x);
  o.h[1] = (f16)((v.y - mu) * rstd * g4.y + b4.y);
  o.h[2] = (f16)((v.z - mu) * rstd * g4.z + b4.z);
  o.h[3] = (f16)((v.w - mu) * rstd * g4.w + b4.w);
  *(u64*)(out + (size_t)row * DMODEL + t * 4) = o.q;
}

// ---------------- GEMM (m97 structure): C = A[M][K] @ Bt[N][K]^T + bias -----
template <int BM, int BN>
__global__ __launch_bounds__(256, 2) void gemm2(const f16* __restrict__ A, int lda,
                                                const f16* __restrict__ Bt, int ldb,
                                                const float* __restrict__ bias,
                                                const float* __restrict__ res,
                                                float* __restrict__ outf,
                                                f16* __restrict__ outh, int ldo,
                                                int N, int K, int relu) {
  constexpr int MT = BM / 32, NT = BN / 32;
  __shared__ f16 As[BM * 64];
  __shared__ f16 Bs[BN * 64];
  const int m0 = blockIdx.y * BM, n0 = blockIdx.x * BN;
  const int t = threadIdx.x;
  const int lane = t & 63, w = t >> 6;
  const int wr = w >> 1, wc = w & 1;
  const int rA = lane & 15, g = lane >> 4;

  f32x4 acc[MT][NT] = {};

  for (int k0 = 0; k0 < K; k0 += 64) {
    __syncthreads();
#pragma unroll
    for (int p = 0; p < BM / 32; p++) {
      const int chunk = p * 256 + w * 64 + lane;
      const int row = chunk >> 3, cb = chunk & 7;
      gload16(A + (size_t)(m0 + row) * lda + k0 + cb * 8,
              As + (size_t)(p * 256 + w * 64) * 8);
    }
#pragma unroll
    for (int p = 0; p < BN / 32; p++) {
      const int chunk = p * 256 + w * 64 + lane;
      const int row = chunk >> 3, cb = chunk & 7;
      gload16(Bt + (size_t)(n0 + row) * ldb + k0 + cb * 8,
              Bs + (size_t)(p * 256 + w * 64) * 8);
    }
    __syncthreads();

#pragma unroll
    for (int ks = 0; ks < 2; ks++) {
      Frag a[MT], b[NT];
#pragma unroll
      for (int mt = 0; mt < MT; mt++) {
        const f16* p = As + (size_t)(wr * (BM / 2) + mt * 16 + rA) * 64 + ks * 32 + 4 * g;
        a[mt].q[0] = *(const u64*)p;
        a[mt].q[1] = *(const u64*)(p + 16);
      }
#pragma unroll
      for (int nt = 0; nt < NT; nt++) {
        const f16* p = Bs + (size_t)(wc * (BN / 2) + nt * 16 + rA) * 64 + ks * 32 + 4 * g;
        b[nt].q[0] = *(const u64*)p;
        b[nt].q[1] = *(const u64*)(p + 16);
      }
#pragma unroll
      for (int mt = 0; mt < MT; mt++)
#pragma unroll
        for (int nt = 0; nt < NT; nt++)
          acc[mt][nt] = mfma16(a[mt].h, b[nt].h, acc[mt][nt]);
    }
  }

#pragma unroll
  for (int mt = 0; mt < MT; mt++) {
#pragma unroll
    for (int nt = 0; nt < NT; nt++) {
      const int col = n0 + wc * (BN / 2) + nt * 16 + rA;
      const int rowb = m0 + wr * (BM / 2) + mt * 16 + g * 4;
      const float bs = bias[col];
#pragma unroll
      for (int r = 0; r < 4; r++) {
        float v = acc[mt][nt][r] + bs;
        if (relu) v = fmaxf(v, 0.0f);
        if (res) v += res[(size_t)(rowb + r) * N + col];
        if (outf) outf[(size_t)(rowb + r) * N + col] = v;
        if (outh) outh[(size_t)(rowb + r) * ldo + col] = (f16)v;
      }
    }
  }
}

// ---------------- V transpose: qkv v-cols -> vt[bh*64+dk][s] ----------------
__global__ __launch_bounds__(256) void vtrans_kernel(const f16* __restrict__ qkv,
                                                     f16* __restrict__ vt) {
  const int bh = blockIdx.y;                 // 0..31
  const int s0 = blockIdx.x * 64;
  const int b = bh >> 4, h = bh & 15;
  __shared__ f16 tile[64][72];               // [s][dk]
  const int t = threadIdx.x;
  for (int pass = 0; pass < 2; pass++) {
    int sl = (t >> 3) + pass * 32;
    int dk0 = (t & 7) * 8;
    u64x2 v = *(const u64x2*)(qkv + (size_t)(b * S_LEN + s0 + sl) * 3072 + 2048 + h * 64 + dk0);
    *(u64x2*)(&tile[sl][dk0]) = v;
  }
  __syncthreads();
  for (int pass = 0; pass < 2; pass++) {
    int dk = (t >> 3) + pass * 32;
    int sc = (t & 7) * 8;
    union { u64x2 q; f16 u[8]; } o;
    for (int j = 0; j < 8; j++) o.u[j] = tile[sc + j][dk];
    *(u64x2*)(vt + (size_t)(bh * 64 + dk) * S_LEN + s0 + sc) = o.q;
  }
}

// ---------------- flash attention: 4 waves, 128 q rows/block ----------------
// K/V tiles (64x64 f16) staged in LDS via global_load_lds, double-buffered,
// one barrier per tile (stage t+1 issued before compute of t).
// Fragment K-mapping: lane (rA,g) holds k in [8g, 8g+8) for BOTH A and B
// (contiguous b128 reads; MFMA is K-permutation-invariant when A/B agree).
// LDS 16B-block XOR swizzle applied on the GLOBAL source + the LDS read
// (both-sides rule, m173): cb_lds = cb_global ^ (row&7).
__global__ __launch_bounds__(256, 2) void attn_kernel(const f16* __restrict__ qkv,
                                                      const f16* __restrict__ vt,
                                                      f16* __restrict__ attn_out) {
  const int qt0 = blockIdx.x * 128;   // q-tile base
  const int bh = blockIdx.y;          // 0..31
  const int b = bh >> 4, h = bh & 15;
  const int t = threadIdx.x;
  const int lane = t & 63, w = t >> 6;
  const int rA = lane & 15, g = lane >> 4;

  __shared__ f16 Ks[2][64 * 64];      // [kv 64][dk 64], swizzled 16B blocks
  __shared__ f16 Vs[2][64 * 64];      // [dk 64][kv 64], swizzled 16B blocks
  __shared__ f16 Ps[4][32 * 72];      // per-wave P: [q 32][kv 64 + pad 8]

  // Q fragments, pre-scaled by 1/8 (exact in f16): rows qt0+w*32+mt*16+rA
  Frag qf[2][2];
#pragma unroll
  for (int mt = 0; mt < 2; mt++)
#pragma unroll
    for (int kt = 0; kt < 2; kt++) {
      const f16* p = qkv + (size_t)(b * S_LEN + qt0 + w * 32 + mt * 16 + rA) * 3072 +
                     h * 64 + kt * 32 + 8 * g;
      f16x8 v = *(const f16x8*)p;
#pragma unroll
      for (int j = 0; j < 8; j++) v[j] = v[j] * (f16)0.125f;
      qf[mt][kt].h = v;
    }

  float mR[2][4], lR[2][4];
  f32x4 o[2][4] = {};
#pragma unroll
  for (int mt = 0; mt < 2; mt++)
#pragma unroll
    for (int r = 0; r < 4; r++) { mR[mt][r] = -3.0e38f; lR[mt][r] = 0.0f; }

  f16* Pw = &Ps[w][0];

#define STAGE_KV(kv0_, buf_)                                                     \
  {                                                                              \
    _Pragma("unroll") for (int i = 0; i < 2; i++) {                              \
      int C = i * 256 + w * 64 + lane;                                           \
      int row = C >> 3;                                                          \
      int cbg = ((C & 7) ^ (row & 7)) * 8;                                       \
      gload16(qkv + (size_t)(b * S_LEN + (kv0_) + row) * 3072 + 1024 + h * 64 + cbg, \
              &Ks[buf_][(i * 256 + w * 64) * 8]);                                \
      gload16(vt + (size_t)(bh * 64 + row) * S_LEN + (kv0_) + cbg,               \
              &Vs[buf_][(i * 256 + w * 64) * 8]);                                \
    }                                                                            \
  }

  int cur = 0;
  STAGE_KV(0, 0);

  for (int kv0 = 0; kv0 < S_LEN; kv0 += 64) {
    __syncthreads();  // buf[cur] staged (drains own vmcnt); prev reads done
    if (kv0 + 64 < S_LEN) STAGE_KV(kv0 + 64, cur ^ 1);  // overlaps compute below

    // ---- QK^T: s[mt][nt] over kv tile
    Frag kf[4][2];
#pragma unroll
    for (int nt = 0; nt < 4; nt++)
#pragma unroll
      for (int kt = 0; kt < 2; kt++) {
        int row = nt * 16 + rA;
        int cbl = (kt * 4 + g) ^ (row & 7);
        kf[nt][kt].h = *(const f16x8*)(&Ks[cur][row * 64 + cbl * 8]);
      }
    f32x4 s[2][4] = {};
#pragma unroll
    for (int mt = 0; mt < 2; mt++)
#pragma unroll
      for (int nt = 0; nt < 4; nt++)
#pragma unroll
        for (int kt = 0; kt < 2; kt++)
          s[mt][nt] = mfma16(qf[mt][kt].h, kf[nt][kt].h, s[mt][nt]);

    // ---- online softmax (C layout: row = mt*16 + g*4 + r, col = nt*16 + rA)
    float alpha[2][4];
#pragma unroll
    for (int mt = 0; mt < 2; mt++)
#pragma unroll
      for (int r = 0; r < 4; r++) {
        float mx = fmaxf(fmaxf(s[mt][0][r], s[mt][1][r]),
                         fmaxf(s[mt][2][r], s[mt][3][r]));
        mx = fmaxf(mx, __shfl_xor(mx, 1));
        mx = fmaxf(mx, __shfl_xor(mx, 2));
        mx = fmaxf(mx, __shfl_xor(mx, 4));
        mx = fmaxf(mx, __shfl_xor(mx, 8));
        float mn = fmaxf(mR[mt][r], mx);
        alpha[mt][r] = exp2f((mR[mt][r] - mn) * 1.44269504f);
        mR[mt][r] = mn;
        float rs = 0.0f;
#pragma unroll
        for (int nt = 0; nt < 4; nt++) {
          float e0 = exp2f((s[mt][nt][r] - mn) * 1.44269504f);
          s[mt][nt][r] = e0;
          rs += e0;
        }
        rs += __shfl_xor(rs, 1);
        rs += __shfl_xor(rs, 2);
        rs += __shfl_xor(rs, 4);
        rs += __shfl_xor(rs, 8);
        lR[mt][r] = lR[mt][r] * alpha[mt][r] + rs;
      }
#pragma unroll
    for (int mt = 0; mt < 2; mt++)
#pragma unroll
      for (int d = 0; d < 4; d++)
#pragma unroll
        for (int r = 0; r < 4; r++) o[mt][d][r] *= alpha[mt][r];

    // ---- P -> per-wave LDS (wave-local; no block barrier needed)
#pragma unroll
    for (int mt = 0; mt < 2; mt++)
#pragma unroll
      for (int nt = 0; nt < 4; nt++)
#pragma unroll
        for (int r = 0; r < 4; r++)
          Pw[(mt * 16 + g * 4 + r) * 72 + nt * 16 + rA] = (f16)s[mt][nt][r];

    // ---- PV: o[mt][d] += P @ V^T
    Frag vf[4][2];
#pragma unroll
    for (int d = 0; d < 4; d++)
#pragma unroll
      for (int ks = 0; ks < 2; ks++) {
        int row = d * 16 + rA;
        int cbl = (ks * 4 + g) ^ (row & 7);
        vf[d][ks].h = *(const f16x8*)(&Vs[cur][row * 64 + cbl * 8]);
      }
    Frag pf[2][2];
#pragma unroll
    for (int mt = 0; mt < 2; mt++)
#pragma unroll
      for (int ks = 0; ks < 2; ks++)
        pf[mt][ks].h = *(const f16x8*)(Pw + (mt * 16 + rA) * 72 + ks * 32 + 8 * g);
#pragma unroll
    for (int mt = 0; mt < 2; mt++)
#pragma unroll
      for (int d = 0; d < 4; d++)
#pragma unroll
        for (int ks = 0; ks < 2; ks++)
          o[mt][d] = mfma16(pf[mt][ks].h, vf[d][ks].h, o[mt][d]);

    cur ^= 1;
  }

  // ---- normalize + store (C layout)
#pragma unroll
  for (int mt = 0; mt < 2; mt++) {
    float inv[4];
#pragma unroll
    for (int r = 0; r < 4; r++) inv[r] = 1.0f / lR[mt][r];
#pragma unroll
    for (int d = 0; d < 4; d++)
#pragma unroll
      for (int r = 0; r < 4; r++) {
        int row = qt0 + w * 32 + mt * 16 + g * 4 + r;
        attn_out[(size_t)(b * S_LEN + row) * DMODEL + h * 64 + d * 16 + rA] =
            (f16)(o[mt][d][r] * inv[r]);
      }
  }
#undef STAGE_KV
}

// ---------------------------------------------------------------------------
extern "C" void kernel_launch(void* const* d_in, const int* in_sizes, int n_in,
                              void* d_out, int out_size, void* d_ws, size_t ws_size,
                              hipStream_t stream) {
  const float* x     = (const float*)d_in[0];
  const float* Wq    = (const float*)d_in[1];
  const float* bq    = (const float*)d_in[2];
  const float* Wk    = (const float*)d_in[3];
  const float* bk    = (const float*)d_in[4];
  const float* Wv    = (const float*)d_in[5];
  const float* bv    = (const float*)d_in[6];
  const float* Wo    = (const float*)d_in[7];
  const float* bo    = (const float*)d_in[8];
  const float* W1    = (const float*)d_in[9];
  const float* b1    = (const float*)d_in[10];
  const float* W2    = (const float*)d_in[11];
  const float* b2    = (const float*)d_in[12];
  const float* ln1g  = (const float*)d_in[13];
  const float* ln1b  = (const float*)d_in[14];
  const float* ln2g  = (const float*)d_in[15];
  const float* ln2b  = (const float*)d_in[16];
  float* out = (float*)d_out;
  char* ws = (char*)d_ws;

  size_t off = 0;
  f16* wqkv_t = (f16*)(ws + off); off += (size_t)3072 * 1024 * 2;   // 6 MB
  f16* wo_t   = (f16*)(ws + off); off += (size_t)1024 * 1024 * 2;   // 2 MB
  f16* w1_t   = (f16*)(ws + off); off += (size_t)4096 * 1024 * 2;   // 8 MB
  f16* w2_t   = (f16*)(ws + off); off += (size_t)1024 * 4096 * 2;   // 8 MB
  float* bqkv = (float*)(ws + off); off += 3072 * 4;                // 12 KB
  f16* regB   = (f16*)(ws + off); off += (size_t)MROWS * 1024 * 2;  // 8 MB (xln/attn_out/xln2)
  f16* qkv    = (f16*)(ws + off); off += (size_t)MROWS * 3072 * 2;  // 24 MB
  f16* vt     = (f16*)(ws + off); off += (size_t)MROWS * 1024 * 2;  // 8 MB
  f16* hbuf   = qkv;  // overlay: qkv+vt (32MB) dead after attention; FFN h = 32MB

  // 1. weights -> f16 transposed
  wtrans_kernel<<<dim3(32, 32), 256, 0, stream>>>(Wq, wqkv_t, 1024, 1024);
  wtrans_kernel<<<dim3(32, 32), 256, 0, stream>>>(Wk, wqkv_t + (size_t)1024 * 1024, 1024, 1024);
  wtrans_kernel<<<dim3(32, 32), 256, 0, stream>>>(Wv, wqkv_t + (size_t)2048 * 1024, 1024, 1024);
  wtrans_kernel<<<dim3(32, 32), 256, 0, stream>>>(Wo, wo_t, 1024, 1024);
  wtrans_kernel<<<dim3(128, 32), 256, 0, stream>>>(W1, w1_t, 1024, 4096);
  wtrans_kernel<<<dim3(32, 128), 256, 0, stream>>>(W2, w2_t, 4096, 1024);
  bias_concat_kernel<<<12, 256, 0, stream>>>(bq, bk, bv, bqkv);

  // 2. LN1(x) -> regB (f16)
  ln_kernel<<<MROWS, 256, 0, stream>>>(x, ln1g, ln1b, regB);

  // 3. fused QKV projection: [4096,1024] @ [1024,3072]
  gemm2<128, 128><<<dim3(24, 32), 256, 0, stream>>>(regB, 1024, wqkv_t, 1024, bqkv,
                                                    nullptr, nullptr, qkv, 3072,
                                                    3072, 1024, 0);
  // 4. V -> [bh*64+dk][s]
  vtrans_kernel<<<dim3(32, 32), 256, 0, stream>>>(qkv, vt);

  // 5. attention -> regB (f16), 4 waves / 128 q-rows per block
  attn_kernel<<<dim3(16, 32), 256, 0, stream>>>(qkv, vt, regB);

  // 6. O projection + residual x -> d_out (fp32); 128x64 tiles -> 512 blocks
  gemm2<128, 64><<<dim3(16, 32), 256, 0, stream>>>(regB, 1024, wo_t, 1024, bo,
                                                   x, out, nullptr, 0,
                                                   1024, 1024, 0);
  // 7. LN2(d_out) -> regB
  ln_kernel<<<MROWS, 256, 0, stream>>>(out, ln2g, ln2b, regB);

  // 8. FFN1 + ReLU: [4096,1024]@[1024,4096] -> hbuf (f16)
  gemm2<128, 128><<<dim3(32, 32), 256, 0, stream>>>(regB, 1024, w1_t, 1024, b1,
                                                    nullptr, nullptr, hbuf, 4096,
                                                    4096, 1024, 1);
  // 9. FFN2 + residual: [4096,4096]@[4096,1024] + d_out -> d_out; 512 blocks
  gemm2<128, 64><<<dim3(16, 32), 256, 0, stream>>>(hbuf, 4096, w2_t, 4096, b2,
                                                   out, out, nullptr, 0,
                                                   1024, 4096, 0);
}

// Round 4
// 341.916 us; speedup vs baseline: 7.2200x; 3.0431x over previous
//
#include <hip/hip_runtime.h>

// Decoder layer: x + attn(LN1(x)); then + FFN(LN2(.))
// B=2, S=2048, D=1024, H=16, DK=64, FF=4096. fp32 in/out; f16 MFMA inside.

#define S_LEN 2048
#define DMODEL 1024
#define NHEADS 16
#define FFDIM 4096
#define MROWS 4096   // B*S

typedef _Float16 f16;
typedef _Float16 f16x8 __attribute__((ext_vector_type(8)));
typedef float f32x4 __attribute__((ext_vector_type(4)));
typedef unsigned long long u64;
typedef unsigned long long u64x2 __attribute__((ext_vector_type(2)));

union Frag { f16x8 h; u64 q[2]; };

__device__ __forceinline__ f32x4 mfma16(f16x8 a, f16x8 b, f32x4 c) {
  return __builtin_amdgcn_mfma_f32_16x16x32_f16(a, b, c, 0, 0, 0);
}

typedef __attribute__((address_space(1))) const void gvoid;
typedef __attribute__((address_space(3))) void lvoid;

__device__ __forceinline__ void gload16(const f16* gp, f16* lp) {
  __builtin_amdgcn_global_load_lds((gvoid*)gp, (lvoid*)lp, 16, 0, 0);
}

// ---------------- weight transpose+convert: W[K][N] fp32 -> Wt[N][K] f16 ----
__global__ __launch_bounds__(256) void wtrans_kernel(const float* __restrict__ W,
                                                     f16* __restrict__ Wt,
                                                     int K, int N) {
  __shared__ f16 tile[32][33];
  const int n0 = blockIdx.x * 32, k0 = blockIdx.y * 32;
  const int tx = threadIdx.x & 31, ty = threadIdx.x >> 5;  // 32 x 8
  for (int i = 0; i < 4; i++) {
    int k = ty + i * 8;
    tile[k][tx] = (f16)W[(size_t)(k0 + k) * N + n0 + tx];
  }
  __syncthreads();
  for (int i = 0; i < 4; i++) {
    int n = ty + i * 8;
    Wt[(size_t)(n0 + n) * K + k0 + tx] = tile[tx][n];
  }
}

__global__ void bias_concat_kernel(const float* __restrict__ bq,
                                   const float* __restrict__ bk,
                                   const float* __restrict__ bv,
                                   float* __restrict__ out) {
  int i = blockIdx.x * 256 + threadIdx.x;  // 3072 total
  float v = (i < 1024) ? bq[i] : (i < 2048) ? bk[i - 1024] : bv[i - 2048];
  out[i] = v;
}

// ---------------- LayerNorm fp32 -> f16 ------------------------------------
__global__ __launch_bounds__(256) void ln_kernel(const float* __restrict__ x,
                                                 const float* __restrict__ gw,
                                                 const float* __restrict__ bw,
                                                 f16* __restrict__ out) {
  const int row = blockIdx.x, t = threadIdx.x;
  const float* xr = x + (size_t)row * DMODEL;
  float4 v = *(const float4*)(xr + t * 4);
  float s = v.x + v.y + v.z + v.w;
  float s2 = v.x * v.x + v.y * v.y + v.z * v.z + v.w * v.w;
  for (int off = 1; off < 64; off <<= 1) {
    s += __shfl_xor(s, off);
    s2 += __shfl_xor(s2, off);
  }
  __shared__ float red[8];
  const int w = t >> 6, lane = t & 63;
  if (lane == 0) { red[w] = s; red[w + 4] = s2; }
  __syncthreads();
  s = red[0] + red[1] + red[2] + red[3];
  s2 = red[4] + red[5] + red[6] + red[7];
  float mu = s * (1.0f / DMODEL);
  float var = s2 * (1.0f / DMODEL) - mu * mu;
  float rstd = rsqrtf(var + 1e-6f);
  float4 g4 = *(const float4*)(gw + t * 4);
  float4 b4 = *(const float4*)(bw + t * 4);
  union { f16 h[4]; u64 q; } o;
  o.h[0] = (f16)((v.x - mu) * rstd * g4.x + b4.x);
  o.h[1] = (f16)((v.y - mu) * rstd * g4.y + b4.y);
  o.h[2] = (f16)((v.z - mu) * rstd * g4.z + b4.z);
  o.h[3] = (f16)((v.w - mu) * rstd * g4.w + b4.w);
  *(u64*)(out + (size_t)row * DMODEL + t * 4) = o.q;
}

// ---------------- GEMM (m97 structure): C = A[M][K] @ Bt[N][K]^T + bias -----
// BK=64, global_load_lds width-16 staging, 2-barrier K-loop, 4 waves (2x2).
// Both-sides XOR swizzle (rule #21): global source 16B-block index XOR'd with
// (row&7); LDS dest linear; fragment reads use the same XOR. Fragment
// K-mapping: lane (rA,g) holds k in [8*(ks*4+g), +8) for BOTH A and B ->
// MFMA dot product is exact (same K-permutation on both operands).
template <int BM, int BN>
__global__ __launch_bounds__(256, 2) void gemm2(const f16* __restrict__ A, int lda,
                                                const f16* __restrict__ Bt, int ldb,
                                                const float* __restrict__ bias,
                                                const float* __restrict__ res,
                                                float* __restrict__ outf,
                                                f16* __restrict__ outh, int ldo,
                                                int N, int K, int relu) {
  constexpr int MT = BM / 32, NT = BN / 32;
  __shared__ f16 As[BM * 64];
  __shared__ f16 Bs[BN * 64];
  const int m0 = blockIdx.y * BM, n0 = blockIdx.x * BN;
  const int t = threadIdx.x;
  const int lane = t & 63, w = t >> 6;
  const int wr = w >> 1, wc = w & 1;
  const int rA = lane & 15, g = lane >> 4;

  f32x4 acc[MT][NT] = {};

  for (int k0 = 0; k0 < K; k0 += 64) {
    __syncthreads();
#pragma unroll
    for (int p = 0; p < BM / 32; p++) {
      const int chunk = p * 256 + w * 64 + lane;
      const int row = chunk >> 3;
      const int cbg = ((chunk & 7) ^ (row & 7)) * 8;  // pre-swizzled source col
      gload16(A + (size_t)(m0 + row) * lda + k0 + cbg,
              As + (size_t)(p * 256 + w * 64) * 8);
    }
#pragma unroll
    for (int p = 0; p < BN / 32; p++) {
      const int chunk = p * 256 + w * 64 + lane;
      const int row = chunk >> 3;
      const int cbg = ((chunk & 7) ^ (row & 7)) * 8;
      gload16(Bt + (size_t)(n0 + row) * ldb + k0 + cbg,
              Bs + (size_t)(p * 256 + w * 64) * 8);
    }
    __syncthreads();

#pragma unroll
    for (int ks = 0; ks < 2; ks++) {
      Frag a[MT], b[NT];
#pragma unroll
      for (int mt = 0; mt < MT; mt++) {
        const int row = wr * (BM / 2) + mt * 16 + rA;
        a[mt].h = *(const f16x8*)(As + row * 64 + ((ks * 4 + g) ^ (row & 7)) * 8);
      }
#pragma unroll
      for (int nt = 0; nt < NT; nt++) {
        const int row = wc * (BN / 2) + nt * 16 + rA;
        b[nt].h = *(const f16x8*)(Bs + row * 64 + ((ks * 4 + g) ^ (row & 7)) * 8);
      }
#pragma unroll
      for (int mt = 0; mt < MT; mt++)
#pragma unroll
        for (int nt = 0; nt < NT; nt++)
          acc[mt][nt] = mfma16(a[mt].h, b[nt].h, acc[mt][nt]);
    }
  }

#pragma unroll
  for (int mt = 0; mt < MT; mt++) {
#pragma unroll
    for (int nt = 0; nt < NT; nt++) {
      const int col = n0 + wc * (BN / 2) + nt * 16 + rA;
      const int rowb = m0 + wr * (BM / 2) + mt * 16 + g * 4;
      const float bs = bias[col];
#pragma unroll
      for (int r = 0; r < 4; r++) {
        float v = acc[mt][nt][r] + bs;
        if (relu) v = fmaxf(v, 0.0f);
        if (res) v += res[(size_t)(rowb + r) * N + col];
        if (outf) outf[(size_t)(rowb + r) * N + col] = v;
        if (outh) outh[(size_t)(rowb + r) * ldo + col] = (f16)v;
      }
    }
  }
}

// ---------------- V transpose: qkv v-cols -> vt[bh*64+dk][s] ----------------
__global__ __launch_bounds__(256) void vtrans_kernel(const f16* __restrict__ qkv,
                                                     f16* __restrict__ vt) {
  const int bh = blockIdx.y;                 // 0..31
  const int s0 = blockIdx.x * 64;
  const int b = bh >> 4, h = bh & 15;
  __shared__ f16 tile[64][72];               // [s][dk]
  const int t = threadIdx.x;
  for (int pass = 0; pass < 2; pass++) {
    int sl = (t >> 3) + pass * 32;
    int dk0 = (t & 7) * 8;
    u64x2 v = *(const u64x2*)(qkv + (size_t)(b * S_LEN + s0 + sl) * 3072 + 2048 + h * 64 + dk0);
    *(u64x2*)(&tile[sl][dk0]) = v;
  }
  __syncthreads();
  for (int pass = 0; pass < 2; pass++) {
    int dk = (t >> 3) + pass * 32;
    int sc = (t & 7) * 8;
    union { u64x2 q; f16 u[8]; } o;
    for (int j = 0; j < 8; j++) o.u[j] = tile[sc + j][dk];
    *(u64x2*)(vt + (size_t)(bh * 64 + dk) * S_LEN + s0 + sc) = o.q;
  }
}

// ---------------- flash attention: 4 waves, 128 q rows/block ----------------
__global__ __launch_bounds__(256, 2) void attn_kernel(const f16* __restrict__ qkv,
                                                      const f16* __restrict__ vt,
                                                      f16* __restrict__ attn_out) {
  const int qt0 = blockIdx.x * 128;   // q-tile base
  const int bh = blockIdx.y;          // 0..31
  const int b = bh >> 4, h = bh & 15;
  const int t = threadIdx.x;
  const int lane = t & 63, w = t >> 6;
  const int rA = lane & 15, g = lane >> 4;

  __shared__ f16 Ks[2][64 * 64];      // [kv 64][dk 64], swizzled 16B blocks
  __shared__ f16 Vs[2][64 * 64];      // [dk 64][kv 64], swizzled 16B blocks
  __shared__ f16 Ps[4][32 * 72];      // per-wave P: [q 32][kv 64 + pad 8]

  // Q fragments, pre-scaled by 1/8 (exact in f16): rows qt0+w*32+mt*16+rA
  Frag qf[2][2];
#pragma unroll
  for (int mt = 0; mt < 2; mt++)
#pragma unroll
    for (int kt = 0; kt < 2; kt++) {
      const f16* p = qkv + (size_t)(b * S_LEN + qt0 + w * 32 + mt * 16 + rA) * 3072 +
                     h * 64 + kt * 32 + 8 * g;
      f16x8 v = *(const f16x8*)p;
#pragma unroll
      for (int j = 0; j < 8; j++) v[j] = v[j] * (f16)0.125f;
      qf[mt][kt].h = v;
    }

  float mR[2][4], lR[2][4];
  f32x4 o[2][4] = {};
#pragma unroll
  for (int mt = 0; mt < 2; mt++)
#pragma unroll
    for (int r = 0; r < 4; r++) { mR[mt][r] = -3.0e38f; lR[mt][r] = 0.0f; }

  f16* Pw = &Ps[w][0];

#define STAGE_KV(kv0_, buf_)                                                     \
  {                                                                              \
    _Pragma("unroll") for (int i = 0; i < 2; i++) {                              \
      int C = i * 256 + w * 64 + lane;                                           \
      int row = C >> 3;                                                          \
      int cbg = ((C & 7) ^ (row & 7)) * 8;                                       \
      gload16(qkv + (size_t)(b * S_LEN + (kv0_) + row) * 3072 + 1024 + h * 64 + cbg, \
              &Ks[buf_][(i * 256 + w * 64) * 8]);                                \
      gload16(vt + (size_t)(bh * 64 + row) * S_LEN + (kv0_) + cbg,               \
              &Vs[buf_][(i * 256 + w * 64) * 8]);                                \
    }                                                                            \
  }

  int cur = 0;
  STAGE_KV(0, 0);

  for (int kv0 = 0; kv0 < S_LEN; kv0 += 64) {
    __syncthreads();  // buf[cur] staged (drains own vmcnt); prev reads done
    if (kv0 + 64 < S_LEN) STAGE_KV(kv0 + 64, cur ^ 1);  // overlaps compute below

    // ---- QK^T: s[mt][nt] over kv tile
    Frag kf[4][2];
#pragma unroll
    for (int nt = 0; nt < 4; nt++)
#pragma unroll
      for (int kt = 0; kt < 2; kt++) {
        int row = nt * 16 + rA;
        int cbl = (kt * 4 + g) ^ (row & 7);
        kf[nt][kt].h = *(const f16x8*)(&Ks[cur][row * 64 + cbl * 8]);
      }
    f32x4 s[2][4] = {};
#pragma unroll
    for (int mt = 0; mt < 2; mt++)
#pragma unroll
      for (int nt = 0; nt < 4; nt++)
#pragma unroll
        for (int kt = 0; kt < 2; kt++)
          s[mt][nt] = mfma16(qf[mt][kt].h, kf[nt][kt].h, s[mt][nt]);

    // ---- online softmax (C layout: row = mt*16 + g*4 + r, col = nt*16 + rA)
    float alpha[2][4];
#pragma unroll
    for (int mt = 0; mt < 2; mt++)
#pragma unroll
      for (int r = 0; r < 4; r++) {
        float mx = fmaxf(fmaxf(s[mt][0][r], s[mt][1][r]),
                         fmaxf(s[mt][2][r], s[mt][3][r]));
        mx = fmaxf(mx, __shfl_xor(mx, 1));
        mx = fmaxf(mx, __shfl_xor(mx, 2));
        mx = fmaxf(mx, __shfl_xor(mx, 4));
        mx = fmaxf(mx, __shfl_xor(mx, 8));
        float mn = fmaxf(mR[mt][r], mx);
        alpha[mt][r] = exp2f((mR[mt][r] - mn) * 1.44269504f);
        mR[mt][r] = mn;
        float rs = 0.0f;
#pragma unroll
        for (int nt = 0; nt < 4; nt++) {
          float e0 = exp2f((s[mt][nt][r] - mn) * 1.44269504f);
          s[mt][nt][r] = e0;
          rs += e0;
        }
        rs += __shfl_xor(rs, 1);
        rs += __shfl_xor(rs, 2);
        rs += __shfl_xor(rs, 4);
        rs += __shfl_xor(rs, 8);
        lR[mt][r] = lR[mt][r] * alpha[mt][r] + rs;
      }
#pragma unroll
    for (int mt = 0; mt < 2; mt++)
#pragma unroll
      for (int d = 0; d < 4; d++)
#pragma unroll
        for (int r = 0; r < 4; r++) o[mt][d][r] *= alpha[mt][r];

    // ---- P -> per-wave LDS (wave-local; no block barrier needed)
#pragma unroll
    for (int mt = 0; mt < 2; mt++)
#pragma unroll
      for (int nt = 0; nt < 4; nt++)
#pragma unroll
        for (int r = 0; r < 4; r++)
          Pw[(mt * 16 + g * 4 + r) * 72 + nt * 16 + rA] = (f16)s[mt][nt][r];

    // ---- PV: o[mt][d] += P @ V^T
    Frag vf[4][2];
#pragma unroll
    for (int d = 0; d < 4; d++)
#pragma unroll
      for (int ks = 0; ks < 2; ks++) {
        int row = d * 16 + rA;
        int cbl = (ks * 4 + g) ^ (row & 7);
        vf[d][ks].h = *(const f16x8*)(&Vs[cur][row * 64 + cbl * 8]);
      }
    Frag pf[2][2];
#pragma unroll
    for (int mt = 0; mt < 2; mt++)
#pragma unroll
      for (int ks = 0; ks < 2; ks++)
        pf[mt][ks].h = *(const f16x8*)(Pw + (mt * 16 + rA) * 72 + ks * 32 + 8 * g);
#pragma unroll
    for (int mt = 0; mt < 2; mt++)
#pragma unroll
      for (int d = 0; d < 4; d++)
#pragma unroll
        for (int ks = 0; ks < 2; ks++)
          o[mt][d] = mfma16(pf[mt][ks].h, vf[d][ks].h, o[mt][d]);

    cur ^= 1;
  }

  // ---- normalize + store (C layout)
#pragma unroll
  for (int mt = 0; mt < 2; mt++) {
    float inv[4];
#pragma unroll
    for (int r = 0; r < 4; r++) inv[r] = 1.0f / lR[mt][r];
#pragma unroll
    for (int d = 0; d < 4; d++)
#pragma unroll
      for (int r = 0; r < 4; r++) {
        int row = qt0 + w * 32 + mt * 16 + g * 4 + r;
        attn_out[(size_t)(b * S_LEN + row) * DMODEL + h * 64 + d * 16 + rA] =
            (f16)(o[mt][d][r] * inv[r]);
      }
  }
#undef STAGE_KV
}

// ---------------------------------------------------------------------------
extern "C" void kernel_launch(void* const* d_in, const int* in_sizes, int n_in,
                              void* d_out, int out_size, void* d_ws, size_t ws_size,
                              hipStream_t stream) {
  const float* x     = (const float*)d_in[0];
  const float* Wq    = (const float*)d_in[1];
  const float* bq    = (const float*)d_in[2];
  const float* Wk    = (const float*)d_in[3];
  const float* bk    = (const float*)d_in[4];
  const float* Wv    = (const float*)d_in[5];
  const float* bv    = (const float*)d_in[6];
  const float* Wo    = (const float*)d_in[7];
  const float* bo    = (const float*)d_in[8];
  const float* W1    = (const float*)d_in[9];
  const float* b1    = (const float*)d_in[10];
  const float* W2    = (const float*)d_in[11];
  const float* b2    = (const float*)d_in[12];
  const float* ln1g  = (const float*)d_in[13];
  const float* ln1b  = (const float*)d_in[14];
  const float* ln2g  = (const float*)d_in[15];
  const float* ln2b  = (const float*)d_in[16];
  float* out = (float*)d_out;
  char* ws = (char*)d_ws;

  size_t off = 0;
  f16* wqkv_t = (f16*)(ws + off); off += (size_t)3072 * 1024 * 2;   // 6 MB
  f16* wo_t   = (f16*)(ws + off); off += (size_t)1024 * 1024 * 2;   // 2 MB
  f16* w1_t   = (f16*)(ws + off); off += (size_t)4096 * 1024 * 2;   // 8 MB
  f16* w2_t   = (f16*)(ws + off); off += (size_t)1024 * 4096 * 2;   // 8 MB
  float* bqkv = (float*)(ws + off); off += 3072 * 4;                // 12 KB
  f16* regB   = (f16*)(ws + off); off += (size_t)MROWS * 1024 * 2;  // 8 MB (xln/attn_out/xln2)
  f16* qkv    = (f16*)(ws + off); off += (size_t)MROWS * 3072 * 2;  // 24 MB
  f16* vt     = (f16*)(ws + off); off += (size_t)MROWS * 1024 * 2;  // 8 MB
  f16* hbuf   = qkv;  // overlay: qkv+vt (32MB) dead after attention; FFN h = 32MB

  // 1. weights -> f16 transposed
  wtrans_kernel<<<dim3(32, 32), 256, 0, stream>>>(Wq, wqkv_t, 1024, 1024);
  wtrans_kernel<<<dim3(32, 32), 256, 0, stream>>>(Wk, wqkv_t + (size_t)1024 * 1024, 1024, 1024);
  wtrans_kernel<<<dim3(32, 32), 256, 0, stream>>>(Wv, wqkv_t + (size_t)2048 * 1024, 1024, 1024);
  wtrans_kernel<<<dim3(32, 32), 256, 0, stream>>>(Wo, wo_t, 1024, 1024);
  wtrans_kernel<<<dim3(128, 32), 256, 0, stream>>>(W1, w1_t, 1024, 4096);
  wtrans_kernel<<<dim3(32, 128), 256, 0, stream>>>(W2, w2_t, 4096, 1024);
  bias_concat_kernel<<<12, 256, 0, stream>>>(bq, bk, bv, bqkv);

  // 2. LN1(x) -> regB (f16)
  ln_kernel<<<MROWS, 256, 0, stream>>>(x, ln1g, ln1b, regB);

  // 3. fused QKV projection: [4096,1024] @ [1024,3072]
  gemm2<128, 128><<<dim3(24, 32), 256, 0, stream>>>(regB, 1024, wqkv_t, 1024, bqkv,
                                                    nullptr, nullptr, qkv, 3072,
                                                    3072, 1024, 0);
  // 4. V -> [bh*64+dk][s]
  vtrans_kernel<<<dim3(32, 32), 256, 0, stream>>>(qkv, vt);

  // 5. attention -> regB (f16), 4 waves / 128 q-rows per block
  attn_kernel<<<dim3(16, 32), 256, 0, stream>>>(qkv, vt, regB);

  // 6. O projection + residual x -> d_out (fp32); 128x64 tiles -> 512 blocks
  gemm2<128, 64><<<dim3(16, 32), 256, 0, stream>>>(regB, 1024, wo_t, 1024, bo,
                                                   x, out, nullptr, 0,
                                                   1024, 1024, 0);
  // 7. LN2(d_out) -> regB
  ln_kernel<<<MROWS, 256, 0, stream>>>(out, ln2g, ln2b, regB);

  // 8. FFN1 + ReLU: [4096,1024]@[1024,4096] -> hbuf (f16)
  gemm2<128, 128><<<dim3(32, 32), 256, 0, stream>>>(regB, 1024, w1_t, 1024, b1,
                                                    nullptr, nullptr, hbuf, 4096,
                                                    4096, 1024, 1);
  // 9. FFN2 + residual: [4096,4096]@[4096,1024] + d_out -> d_out; 512 blocks
  gemm2<128, 64><<<dim3(16, 32), 256, 0, stream>>>(hbuf, 4096, w2_t, 4096, b2,
                                                   out, out, nullptr, 0,
                                                   1024, 4096, 0);
}